// Round 7
// baseline (387.733 us; speedup 1.0000x reference)
//
#include <hip/hip_runtime.h>
#include <hip/hip_bf16.h>

#define T 128
#define F 64
#define H1 32
#define G1 128   // 4*H1
#define H2 16
#define G2 64    // 4*H2

typedef __attribute__((ext_vector_type(8))) short bf16x8;
typedef __attribute__((ext_vector_type(4))) float f32x4;

#define MFMA __builtin_amdgcn_mfma_f32_16x16x32_bf16

#define LOG2E   1.4426950408889634f
#define TWOLOG2E 2.8853900817779268f

// Raw v_exp_f32 (exp2). Gate pre-activations are pre-scaled by log2e (sigmoid
// gates) / 2*log2e (g gate) via the WEIGHTS, so no per-element multiply.
__device__ __forceinline__ float exp2_(float x) {
    float r; asm("v_exp_f32 %0, %1" : "=v"(r) : "v"(x)); return r;
}
__device__ __forceinline__ float exp2n_(float x) {   // exp2(-x), free modifier
    float r; asm("v_exp_f32 %0, -%1" : "=v"(r) : "v"(x)); return r;
}
// z' = log2e * z  ->  sigmoid(z)
__device__ __forceinline__ float sig2_(float zp) {
    return __builtin_amdgcn_rcpf(1.0f + exp2n_(zp));
}
// z' = 2*log2e * z  ->  tanh(z)
__device__ __forceinline__ float tanh2_(float zp) {
    return 1.0f - 2.0f * __builtin_amdgcn_rcpf(exp2_(zp) + 1.0f);
}
// plain-domain sigmoid for the head
__device__ __forceinline__ float sigmoidf_(float x) {
    return __builtin_amdgcn_rcpf(1.0f + exp2n_(x * LOG2E));
}
__device__ __forceinline__ unsigned short f2bf(float f) {
    union { float f; unsigned u; } c; c.f = f;
    unsigned r = c.u + 0x7FFF + ((c.u >> 16) & 1);   // RTNE
    return (unsigned short)(r >> 16);
}
// v_cvt_pk_bf16_f32: two f32 -> one dword of 2 bf16 (RTNE), single VALU op.
__device__ __forceinline__ unsigned cvtpk(float lo, float hi) {
    unsigned r;
    asm("v_cvt_pk_bf16_f32 %0, %1, %2" : "=v"(r) : "v"(lo), "v"(hi));
    return r;
}
__device__ __forceinline__ bf16x8 pack8(float4 a, float4 b) {
    union { unsigned u[4]; bf16x8 v; } z;
    z.u[0] = cvtpk(a.x, a.y); z.u[1] = cvtpk(a.z, a.w);
    z.u[2] = cvtpk(b.x, b.y); z.u[3] = cvtpk(b.z, b.w);
    return z.v;
}
// LDS-only barrier: waits DS ops, does NOT drain vmcnt.
__device__ __forceinline__ void lds_barrier() {
    asm volatile("s_waitcnt lgkmcnt(0)" ::: "memory");
    __builtin_amdgcn_s_barrier();
}

struct XR { float4 a, b, c, d; };   // one step's raw x (16 fp32)

// =============================================================================
// K1: layer-1 recurrence with IN-KERNEL x conversion (xcvt eliminated).
// Lane (n15,quad)'s A-fragment = x[g*16+n15][t][quad*8 + 32*ks + 0..7] — 8
// consecutive floats per half -> two float4 loads + 4 cvt_pk each. Loads are
// issued 4 steps ahead (raw fp32 regs), converted 2 steps before use.
// Block = (g, d), 4 waves (gh = gate-half, sh = sample-half); 2 blocks/CU.
// xa = bias + x(t)W built one step ahead; post-barrier path is
// ds_read -> 1 U-MFMA -> activation. Weights pre-scaled to exp2 domain.
// =============================================================================
__global__ __launch_bounds__(256, 2) void lstm1_fused(
    const float* __restrict__ x,          // [B][T][64]
    const float* __restrict__ W1f, const float* __restrict__ b1f, const float* __restrict__ U1f,
    const float* __restrict__ W1b, const float* __restrict__ b1b, const float* __restrict__ U1b,
    unsigned short* __restrict__ h1)     // packed per (g,t), 1024 shorts
{
    __shared__ unsigned short hb[2][16 * 40];
    const int tid  = threadIdx.x;
    const int lane = tid & 63;
    const int wv   = __builtin_amdgcn_readfirstlane(tid >> 6);
    const int gh   = wv & 1;
    const int sh   = wv >> 1;            // 0..1
    const int n15  = lane & 15, quad = lane >> 4;
    const int d    = blockIdx.x & 1, g = blockIdx.x >> 1;

    const float* W  = d ? W1b : W1f;
    const float* U  = d ? U1b : U1f;
    const float* bs = d ? b1b : b1f;

    // frag q = 2*i + gh covers gate cols q*16+n15; gate index == i
    bf16x8 Wf[4][2], Uf[4];
    f32x4 biasC[4];
    #pragma unroll
    for (int i = 0; i < 4; ++i) {
        const float sc = (i == 2) ? TWOLOG2E : LOG2E;
        const int col = (2 * i + gh) * 16 + n15;
        biasC[i] = (f32x4)(bs[col] * sc);
        #pragma unroll
        for (int ks = 0; ks < 2; ++ks) {
            bf16x8 f;
            #pragma unroll
            for (int j = 0; j < 8; ++j)
                f[j] = (short)f2bf(W[(ks * 32 + quad * 8 + j) * G1 + col] * sc);
            Wf[i][ks] = f;
        }
        bf16x8 u;
        #pragma unroll
        for (int j = 0; j < 8; ++j)
            u[j] = (short)f2bf(U[(quad * 8 + j) * G1 + col] * sc);
        Uf[i] = u;
    }

    // zero h(-1) buffer + pads (1280 shorts total)
    #pragma unroll
    for (int i = 0; i < 5; ++i) ((unsigned short*)hb)[tid + i * 256] = 0;

    float c0 = 0.0f, c1 = 0.0f;
    // lane's x row: sample g*16+n15, element offset quad*8 (+32 for ks=1)
    const float* xbase = x + ((size_t)(g * 16 + n15) * T) * 64 + quad * 8;
    unsigned short* h1b0 = h1 + (size_t)g * T * 1024
        + d * 512 + ((quad * 4 + 2 * sh) + 16 * (gh * 2 + (n15 >> 3))) * 8 + (n15 & 7);
    unsigned short* h1b1 = h1b0 + 8;

    // prologue: xa for steps 0/1 (load+convert now); raw x for steps 2/3
    f32x4 xaA[4], xaB[4];
    XR rawA, rawB;
    {
        const float* p0 = xbase + (size_t)(d ? (T - 1) : 0) * 64;
        bf16x8 t0 = pack8(*(const float4*)p0, *(const float4*)(p0 + 4));
        bf16x8 t1 = pack8(*(const float4*)(p0 + 32), *(const float4*)(p0 + 36));
        #pragma unroll
        for (int i = 0; i < 4; ++i) {
            xaA[i] = MFMA(t0, Wf[i][0], biasC[i], 0, 0, 0);
            xaA[i] = MFMA(t1, Wf[i][1], xaA[i], 0, 0, 0);
        }
        const float* p1 = xbase + (size_t)(d ? (T - 2) : 1) * 64;
        t0 = pack8(*(const float4*)p1, *(const float4*)(p1 + 4));
        t1 = pack8(*(const float4*)(p1 + 32), *(const float4*)(p1 + 36));
        #pragma unroll
        for (int i = 0; i < 4; ++i) {
            xaB[i] = MFMA(t0, Wf[i][0], biasC[i], 0, 0, 0);
            xaB[i] = MFMA(t1, Wf[i][1], xaB[i], 0, 0, 0);
        }
        const float* p2 = xbase + (size_t)(d ? (T - 3) : 2) * 64;
        rawA.a = *(const float4*)p2;        rawA.b = *(const float4*)(p2 + 4);
        rawA.c = *(const float4*)(p2 + 32); rawA.d = *(const float4*)(p2 + 36);
        const float* p3 = xbase + (size_t)(d ? (T - 4) : 3) * 64;
        rawB.a = *(const float4*)p3;        rawB.b = *(const float4*)(p3 + 4);
        rawB.c = *(const float4*)(p3 + 32); rawB.d = *(const float4*)(p3 + 36);
    }
    lds_barrier();

    auto step = [&](int s, f32x4* xa, XR& r) {
        // critical path: ds_read(h) -> 1 U-MFMA -> activation
        const bf16x8 af = *(const bf16x8*)(hb[s & 1] + n15 * 40 + quad * 8);
        f32x4 a0 = MFMA(af, Uf[0], xa[0], 0, 0, 0);
        f32x4 a1 = MFMA(af, Uf[1], xa[1], 0, 0, 0);
        f32x4 a2 = MFMA(af, Uf[2], xa[2], 0, 0, 0);
        f32x4 a3 = MFMA(af, Uf[3], xa[3], 0, 0, 0);

        // convert raw x(s+2) (loaded 2 steps ago, vmcnt long satisfied)
        const bf16x8 x0 = pack8(r.a, r.b);
        const bf16x8 x1 = pack8(r.c, r.d);
        xa[0] = MFMA(x0, Wf[0][0], biasC[0], 0, 0, 0);
        xa[1] = MFMA(x0, Wf[1][0], biasC[1], 0, 0, 0);
        xa[2] = MFMA(x0, Wf[2][0], biasC[2], 0, 0, 0);
        xa[3] = MFMA(x0, Wf[3][0], biasC[3], 0, 0, 0);
        xa[0] = MFMA(x1, Wf[0][1], xa[0], 0, 0, 0);
        xa[1] = MFMA(x1, Wf[1][1], xa[1], 0, 0, 0);
        xa[2] = MFMA(x1, Wf[2][1], xa[2], 0, 0, 0);
        xa[3] = MFMA(x1, Wf[3][1], xa[3], 0, 0, 0);

        // prefetch raw x(s+4)
        if (s + 4 < T) {
            const float* pn = xbase + (size_t)(d ? (T - 5 - s) : (s + 4)) * 64;
            r.a = *(const float4*)pn;        r.b = *(const float4*)(pn + 4);
            r.c = *(const float4*)(pn + 32); r.d = *(const float4*)(pn + 36);
        }

        const int t = d ? (T - 1 - s) : s;
        float zi0, zi1, zf0, zf1, zg0, zg1, zo0, zo1;
        if (sh == 0) {
            zi0 = a0[0]; zi1 = a0[1]; zf0 = a1[0]; zf1 = a1[1];
            zg0 = a2[0]; zg1 = a2[1]; zo0 = a3[0]; zo1 = a3[1];
        } else {
            zi0 = a0[2]; zi1 = a0[3]; zf0 = a1[2]; zf1 = a1[3];
            zg0 = a2[2]; zg1 = a2[3]; zo0 = a3[2]; zo1 = a3[3];
        }
        {   // sample quad*4 + 2*sh
            const float ig = sig2_(zi0), fg = sig2_(zf0);
            const float gg = tanh2_(zg0), og = sig2_(zo0);
            c0 = fg * c0 + ig * gg;
            const float h = og * tanh2_(c0 * TWOLOG2E);
            const unsigned short us = f2bf(h);
            hb[(s + 1) & 1][(quad * 4 + 2 * sh) * 40 + gh * 16 + n15] = us;
            h1b0[(size_t)t * 1024] = us;
        }
        {   // sample quad*4 + 2*sh + 1
            const float ig = sig2_(zi1), fg = sig2_(zf1);
            const float gg = tanh2_(zg1), og = sig2_(zo1);
            c1 = fg * c1 + ig * gg;
            const float h = og * tanh2_(c1 * TWOLOG2E);
            const unsigned short us = f2bf(h);
            hb[(s + 1) & 1][(quad * 4 + 2 * sh + 1) * 40 + gh * 16 + n15] = us;
            h1b1[(size_t)t * 1024] = us;
        }
        lds_barrier();
    };

    #pragma unroll 1
    for (int s = 0; s < T; s += 2) {
        step(s, xaA, rawA);
        step(s + 1, xaB, rawB);
    }
}

// =============================================================================
// K2: layer-2 recurrence, r1-lstm1 shape: block = (g, d), 512 blocks x 4
// waves (sh = 0..3) -> 2 blocks/CU. MFMAs duplicated across sh; activation
// 1 elem/lane. U2 zero-padded to K=32 via zeroed LDS cols 16..39.
// =============================================================================
__global__ __launch_bounds__(256, 2) void lstm2_rec(
    const unsigned short* __restrict__ h1,
    const float* __restrict__ W2f, const float* __restrict__ b2f, const float* __restrict__ U2f,
    const float* __restrict__ W2b, const float* __restrict__ b2b, const float* __restrict__ U2b,
    float* __restrict__ hfin)            // [ns][32]
{
    __shared__ unsigned short hx[2][16 * 40];   // cols 16..39 stay zero
    const int tid  = threadIdx.x;
    const int lane = tid & 63;
    const int sh   = __builtin_amdgcn_readfirstlane(tid >> 6);   // 0..3
    const int n15  = lane & 15, quad = lane >> 4;
    const int d    = blockIdx.x & 1, g = blockIdx.x >> 1;

    const float* W  = d ? W2b : W2f;
    const float* U  = d ? U2b : U2f;
    const float* bs = d ? b2b : b2f;

    bf16x8 Wf[4][2], Uf[4];
    f32x4 biasC[4];
    #pragma unroll
    for (int i = 0; i < 4; ++i) {
        const float sc = (i == 2) ? TWOLOG2E : LOG2E;
        const int col = i * 16 + n15;        // gate i, unit n15
        biasC[i] = (f32x4)(bs[col] * sc);
        #pragma unroll
        for (int ks = 0; ks < 2; ++ks) {
            bf16x8 f;
            #pragma unroll
            for (int j = 0; j < 8; ++j)
                f[j] = (short)f2bf(W[(ks * 32 + quad * 8 + j) * G2 + col] * sc);
            Wf[i][ks] = f;
        }
        bf16x8 uu;
        #pragma unroll
        for (int j = 0; j < 8; ++j) {
            const int k = quad * 8 + j;
            uu[j] = (k < H2) ? (short)f2bf(U[k * G2 + col] * sc) : (short)0;
        }
        Uf[i] = uu;
    }

    // zero both buffers: 1280 shorts / 256 threads = 5 each
    #pragma unroll
    for (int i = 0; i < 5; ++i) ((unsigned short*)hx)[tid + i * 256] = 0;

    float c = 0.0f, hlast = 0.0f;
    const unsigned short* hl = h1 + (size_t)g * T * 1024 + lane * 8;

    f32x4 xaA[4], xaB[4];
    bf16x8 hA0, hA1, hB0, hB1;
    {
        const unsigned short* p0 = hl + (size_t)(d ? (T - 1) : 0) * 1024;
        bf16x8 t0 = *(const bf16x8*)(p0), t1 = *(const bf16x8*)(p0 + 512);
        #pragma unroll
        for (int i = 0; i < 4; ++i) {
            xaA[i] = MFMA(t0, Wf[i][0], biasC[i], 0, 0, 0);
            xaA[i] = MFMA(t1, Wf[i][1], xaA[i], 0, 0, 0);
        }
        const unsigned short* p1 = hl + (size_t)(d ? (T - 2) : 1) * 1024;
        t0 = *(const bf16x8*)(p1); t1 = *(const bf16x8*)(p1 + 512);
        #pragma unroll
        for (int i = 0; i < 4; ++i) {
            xaB[i] = MFMA(t0, Wf[i][0], biasC[i], 0, 0, 0);
            xaB[i] = MFMA(t1, Wf[i][1], xaB[i], 0, 0, 0);
        }
        const unsigned short* p2 = hl + (size_t)(d ? (T - 3) : 2) * 1024;
        hA0 = *(const bf16x8*)(p2); hA1 = *(const bf16x8*)(p2 + 512);
        const unsigned short* p3 = hl + (size_t)(d ? (T - 4) : 3) * 1024;
        hB0 = *(const bf16x8*)(p3); hB1 = *(const bf16x8*)(p3 + 512);
    }
    lds_barrier();

    auto step = [&](int s, f32x4* xa, bf16x8& x0, bf16x8& x1) {
        const bf16x8 af = *(const bf16x8*)(hx[s & 1] + n15 * 40 + quad * 8);
        f32x4 a0 = MFMA(af, Uf[0], xa[0], 0, 0, 0);
        f32x4 a1 = MFMA(af, Uf[1], xa[1], 0, 0, 0);
        f32x4 a2 = MFMA(af, Uf[2], xa[2], 0, 0, 0);
        f32x4 a3 = MFMA(af, Uf[3], xa[3], 0, 0, 0);

        xa[0] = MFMA(x0, Wf[0][0], biasC[0], 0, 0, 0);
        xa[1] = MFMA(x0, Wf[1][0], biasC[1], 0, 0, 0);
        xa[2] = MFMA(x0, Wf[2][0], biasC[2], 0, 0, 0);
        xa[3] = MFMA(x0, Wf[3][0], biasC[3], 0, 0, 0);
        xa[0] = MFMA(x1, Wf[0][1], xa[0], 0, 0, 0);
        xa[1] = MFMA(x1, Wf[1][1], xa[1], 0, 0, 0);
        xa[2] = MFMA(x1, Wf[2][1], xa[2], 0, 0, 0);
        xa[3] = MFMA(x1, Wf[3][1], xa[3], 0, 0, 0);

        if (s + 4 < T) {
            const unsigned short* pn = hl + (size_t)(d ? (T - 5 - s) : (s + 4)) * 1024;
            x0 = *(const bf16x8*)(pn); x1 = *(const bf16x8*)(pn + 512);
        }

        // wave-uniform row select: wave sh owns sample quad*4+sh
        float z0, z1, z2, z3;
        if (sh == 0)      { z0 = a0[0]; z1 = a1[0]; z2 = a2[0]; z3 = a3[0]; }
        else if (sh == 1) { z0 = a0[1]; z1 = a1[1]; z2 = a2[1]; z3 = a3[1]; }
        else if (sh == 2) { z0 = a0[2]; z1 = a1[2]; z2 = a2[2]; z3 = a3[2]; }
        else              { z0 = a0[3]; z1 = a1[3]; z2 = a2[3]; z3 = a3[3]; }
        const float ig = sig2_(z0), fg = sig2_(z1);
        const float gg = tanh2_(z2), og = sig2_(z3);
        c = fg * c + ig * gg;
        hlast = og * tanh2_(c * TWOLOG2E);
        hx[(s + 1) & 1][(quad * 4 + sh) * 40 + n15] = f2bf(hlast);
        lds_barrier();
    };

    #pragma unroll 1
    for (int s = 0; s < T; s += 2) {
        step(s, xaA, hA0, hA1);
        step(s + 1, xaB, hB0, hB1);
    }

    hfin[(size_t)(g * 16 + quad * 4 + sh) * 32 + d * 16 + n15] = hlast;
}

// =============================================================================
// K3: dense head. One thread per sample: [32] -> swish(W3) -> sigmoid(W4).
// =============================================================================
__global__ __launch_bounds__(256) void head(
    const float* __restrict__ hfin,
    const float* __restrict__ W3, const float* __restrict__ b3,
    const float* __restrict__ W4, const float* __restrict__ b4,
    float* __restrict__ out, const int ns)
{
    const int i = blockIdx.x * 256 + threadIdx.x;
    if (i >= ns) return;
    float h[32];
    #pragma unroll
    for (int k = 0; k < 8; ++k)
        *(float4*)(h + k * 4) = *(const float4*)(hfin + (size_t)i * 32 + k * 4);
    float y[8];
    #pragma unroll
    for (int u = 0; u < 8; ++u) {
        float a = b3[u];
        #pragma unroll
        for (int k = 0; k < 32; ++k) a += h[k] * W3[k * 8 + u];
        y[u] = a * sigmoidf_(a);
    }
    #pragma unroll
    for (int o = 0; o < 2; ++o) {
        float a = b4[o];
        #pragma unroll
        for (int u = 0; u < 8; ++u) a += y[u] * W4[u * 2 + o];
        out[(size_t)i * 2 + o] = sigmoidf_(a);
    }
}

extern "C" void kernel_launch(void* const* d_in, const int* in_sizes, int n_in,
                              void* d_out, int out_size, void* d_ws, size_t ws_size,
                              hipStream_t stream) {
    const float* x   = (const float*)d_in[0];
    const float* W1f = (const float*)d_in[1];
    const float* U1f = (const float*)d_in[2];
    const float* b1f = (const float*)d_in[3];
    const float* W1b = (const float*)d_in[4];
    const float* U1b = (const float*)d_in[5];
    const float* b1b = (const float*)d_in[6];
    const float* W2f = (const float*)d_in[7];
    const float* U2f = (const float*)d_in[8];
    const float* b2f = (const float*)d_in[9];
    const float* W2b = (const float*)d_in[10];
    const float* U2b = (const float*)d_in[11];
    const float* b2b = (const float*)d_in[12];
    const float* W3  = (const float*)d_in[13];
    const float* b3  = (const float*)d_in[14];
    const float* W4  = (const float*)d_in[15];
    const float* b4  = (const float*)d_in[16];
    float* out = (float*)d_out;

    const int B  = in_sizes[0] / (T * F);
    const int NG = B / 16;                       // sample groups

    // ws layout: h1 (256 KB/group) + hfin (2 KB/group), chunked if ws small
    const size_t perG = (size_t)T * 1024 * sizeof(unsigned short);  // 256 KB
    const size_t hfG  = 16 * 32 * sizeof(float);                    // 2 KB
    int chG = (int)(ws_size / (perG + hfG));
    if (chG > NG) chG = NG;
    if (chG < 1) chG = 1;
    unsigned short* h1 = (unsigned short*)d_ws;
    float* hfin = (float*)((char*)d_ws + (size_t)chG * perG);

    for (int g0 = 0; g0 < NG; g0 += chG) {
        const int cg = (NG - g0 < chG) ? (NG - g0) : chG;
        lstm1_fused<<<cg * 2, 256, 0, stream>>>(
            x + (size_t)g0 * 16 * T * F, W1f, b1f, U1f, W1b, b1b, U1b, h1);
        lstm2_rec<<<cg * 2, 256, 0, stream>>>(
            h1, W2f, b2f, U2f, W2b, b2b, U2b, hfin);
        head<<<(cg * 16 + 255) / 256, 256, 0, stream>>>(
            hfin, W3, b3, W4, b4, out + (size_t)g0 * 16 * 2, cg * 16);
    }
}